// Round 1
// 854.394 us; speedup vs baseline: 1.1772x; 1.1772x over previous
//
#include <hip/hip_runtime.h>
#include <hip/hip_bf16.h>
#include <cstdint>
#include <cstddef>

typedef __attribute__((ext_vector_type(8))) __bf16 bf16x8;
typedef __attribute__((ext_vector_type(8))) unsigned short ushort8;
typedef __attribute__((ext_vector_type(4))) float f32x4;

#define DEVINL __device__ __forceinline__

DEVINL unsigned short f2bf(float f) {
    union { float f; unsigned int i; } v; v.f = f;
    unsigned int u = v.i;
    unsigned int r = (u + 0x7fffu + ((u >> 16) & 1u)) >> 16;
    return (unsigned short)r;
}

// C[m][n] = sum_k A[m][k] * Bt[n][k]
// A: [M,K] row-major, fp32 if AF32 (converted to bf16 during staging) else bf16
// Bt: [N,K] row-major bf16
// KS == 1:
//   EPI 0: write Ct[n][m] bf16 (stride M)
// KS > 1 (split-K over blockIdx.z):
//   write fp32 partial at Cv + z*Ncols*M, layout [n][m] (stride M)
template<int BM, int BN, int EPI, bool AF32, int KS>
__global__ __launch_bounds__(256)
void gemm_bt(const void* __restrict__ Av, const short* __restrict__ Bt,
             void* __restrict__ Cv, const float* __restrict__ fvec,
             int M, int K, int Ncols)
{
    constexpr int BK = 64;                 // 8 chunks of 8 elements (16B bf16) per row
    constexpr int WTM = BM / 2;            // 2x2 wave grid
    constexpr int WTN = BN / 2;
    constexpr int FM = WTM / 16;
    constexpr int FN = WTN / 16;
    constexpr int CA = (BM * 8) / 256;     // LDS 16B chunks per thread, A tile
    constexpr int CB = (BN * 8) / 256;

    __shared__ __align__(16) short smem[(BM + BN) * BK];
    short* smA = smem;
    short* smB = smem + BM * BK;

    const int t  = threadIdx.x;
    const int m0 = blockIdx.x * BM;
    const int n0 = blockIdx.y * BN;
    const int z  = (KS > 1) ? blockIdx.z : 0;
    const int Kc = K / KS;
    const int kbeg = z * Kc;
    const int kend = kbeg + Kc;

    const int w    = t >> 6;
    const int lane = t & 63;
    const int wm   = w >> 1;
    const int wn   = w & 1;
    const int lr   = lane & 15;
    const int q    = lane >> 4;

    f32x4 acc[FM][FN];
#pragma unroll
    for (int i = 0; i < FM; ++i)
#pragma unroll
        for (int j = 0; j < FN; ++j)
            acc[i][j] = f32x4{0.f, 0.f, 0.f, 0.f};

    // LDS fragment read offsets (XOR swizzle: LDS chunk lc holds global chunk lc^(row&7))
    int aoff[FM][2], boff[FN][2];
#pragma unroll
    for (int i = 0; i < FM; ++i) {
        int row = wm * WTM + i * 16 + lr;
#pragma unroll
        for (int s = 0; s < 2; ++s)
            aoff[i][s] = row * BK + (((s * 4 + q) ^ (row & 7)) * 8);
    }
#pragma unroll
    for (int j = 0; j < FN; ++j) {
        int row = wn * WTN + j * 16 + lr;
#pragma unroll
        for (int s = 0; s < 2; ++s)
            boff[j][s] = row * BK + (((s * 4 + q) ^ (row & 7)) * 8);
    }

    // staging: thread t fills LDS chunk c = i*256+t, from global chunk gc = (c&7)^(row&7)
    const float* aSrcF[CA]; const short* aSrcH[CA]; short* aDst[CA];
#pragma unroll
    for (int i = 0; i < CA; ++i) {
        int c = i * 256 + t;
        int row = c >> 3;
        int gc = (c & 7) ^ (row & 7);
        size_t eoff = (size_t)(m0 + row) * K + gc * 8;
        if constexpr (AF32) aSrcF[i] = (const float*)Av + eoff;
        else                aSrcH[i] = (const short*)Av + eoff;
        aDst[i] = smA + c * 8;
    }
    const short* bSrc[CB]; short* bDst[CB];
#pragma unroll
    for (int i = 0; i < CB; ++i) {
        int c = i * 256 + t;
        int row = c >> 3;
        int gc = (c & 7) ^ (row & 7);
        bSrc[i] = Bt + (size_t)(n0 + row) * K + gc * 8;
        bDst[i] = smB + c * 8;
    }

    for (int k0 = kbeg; k0 < kend; k0 += BK) {
        // global -> VGPR (with fp32->bf16 conversion for A if AF32)
        ushort8 ra[CA], rb[CB];
#pragma unroll
        for (int i = 0; i < CA; ++i) {
            if constexpr (AF32) {
                f32x4 lo = *(const f32x4*)(const void*)(aSrcF[i] + k0);
                f32x4 hi = *(const f32x4*)(const void*)(aSrcF[i] + k0 + 4);
                ushort8 r;
                r[0] = f2bf(lo[0]); r[1] = f2bf(lo[1]); r[2] = f2bf(lo[2]); r[3] = f2bf(lo[3]);
                r[4] = f2bf(hi[0]); r[5] = f2bf(hi[1]); r[6] = f2bf(hi[2]); r[7] = f2bf(hi[3]);
                ra[i] = r;
            } else {
                ra[i] = *(const ushort8*)(const void*)(aSrcH[i] + k0);
            }
        }
#pragma unroll
        for (int i = 0; i < CB; ++i) rb[i] = *(const ushort8*)(const void*)(bSrc[i] + k0);

        __syncthreads();   // previous iteration's LDS reads complete
#pragma unroll
        for (int i = 0; i < CA; ++i) *(ushort8*)(void*)aDst[i] = ra[i];
#pragma unroll
        for (int i = 0; i < CB; ++i) *(ushort8*)(void*)bDst[i] = rb[i];
        __syncthreads();   // stores visible

#pragma unroll
        for (int s = 0; s < 2; ++s) {
            bf16x8 fa[FM], fb[FN];
#pragma unroll
            for (int i = 0; i < FM; ++i)
                fa[i] = *(const bf16x8*)(const void*)(smA + aoff[i][s]);
#pragma unroll
            for (int j = 0; j < FN; ++j)
                fb[j] = *(const bf16x8*)(const void*)(smB + boff[j][s]);
#pragma unroll
            for (int i = 0; i < FM; ++i)
#pragma unroll
                for (int j = 0; j < FN; ++j)
                    acc[i][j] = __builtin_amdgcn_mfma_f32_16x16x32_bf16(
                        fa[i], fb[j], acc[i][j], 0, 0, 0);
        }
    }

    // epilogue. C/D frag layout: C[m = (lane>>4)*4 + reg][n = lane&15]
#pragma unroll
    for (int i = 0; i < FM; ++i) {
        const int m_base = m0 + wm * WTM + i * 16 + q * 4;
        float s0 = 1.f, s1 = 1.f, s2 = 1.f, s3 = 1.f;
        if constexpr (EPI == 1 && KS == 1) {
            s0 = fvec[m_base + 0];
            s1 = fvec[m_base + 1];
            s2 = fvec[m_base + 2];
            s3 = fvec[m_base + 3];
        }
#pragma unroll
        for (int j = 0; j < FN; ++j) {
            const int n_g = n0 + wn * WTN + j * 16 + lr;
            f32x4 v = acc[i][j];
            if constexpr (KS > 1) {
                float* P = (float*)Cv + (size_t)z * Ncols * M;
                *(f32x4*)(P + (size_t)n_g * M + m_base) = v;
            } else if constexpr (EPI == 0 || EPI == 1) {
                ushort4 o4;
                o4.x = f2bf(v[0] * s0);
                o4.y = f2bf(v[1] * s1);
                o4.z = f2bf(v[2] * s2);
                o4.w = f2bf(v[3] * s3);
                *(ushort4*)((unsigned short*)Cv + (size_t)n_g * M + m_base) = o4;
            }
        }
    }
}

// transpose fp32 [R,C] -> bf16 [C,R]
__global__ __launch_bounds__(256)
void transpose_f32_to_bf16(const float* __restrict__ in,
                           unsigned short* __restrict__ out, int R, int C)
{
    int idx = blockIdx.x * 256 + threadIdx.x;
    if (idx < R * C) {
        int r = idx / C, c = idx - r * C;
        out[(size_t)c * R + r] = f2bf(in[idx]);
    }
}

// out[n][m] bf16 = (SCALE ? f[m] : 1) * sum_z p[z][n][m]
// p: fp32, z-plane stride zs. M hardcoded 8192 (m = idx & 8191).
template<int KS, bool SCALE>
__global__ __launch_bounds__(256)
void reduce_scaleT(const float* __restrict__ p, unsigned short* __restrict__ out,
                   const float* __restrict__ fvec, size_t zs)
{
    size_t base = ((size_t)blockIdx.x * 256 + threadIdx.x) * 4;
    f32x4 s = *(const f32x4*)(p + base);
#pragma unroll
    for (int zz = 1; zz < KS; ++zz)
        s += *(const f32x4*)(p + (size_t)zz * zs + base);
    if constexpr (SCALE) {
        const int m = (int)(base & 8191);
        f32x4 f = *(const f32x4*)(fvec + m);
        s[0] *= f[0]; s[1] *= f[1]; s[2] *= f[2]; s[3] *= f[3];
    }
    ushort4 o4;
    o4.x = f2bf(s[0]); o4.y = f2bf(s[1]); o4.z = f2bf(s[2]); o4.w = f2bf(s[3]);
    *(ushort4*)(out + base) = o4;
}

// out[m][h] bf16 row-major = relu(sum_z p[z][h][m]);  p fp32 [KS][H][M]
template<int KS>
__global__ __launch_bounds__(256)
void reduce_relu_trans(const float* __restrict__ p, unsigned short* __restrict__ out,
                       int M, int H)
{
    __shared__ float tile[64][65];
    const int t  = threadIdx.x;
    const int m0 = blockIdx.x * 64;
    const int n0 = blockIdx.y * 64;
    const size_t zs = (size_t)H * M;
#pragma unroll
    for (int pass = 0; pass < 4; ++pass) {
        int n  = pass * 16 + (t >> 4);
        int mo = (t & 15) * 4;
        const float* src = p + (size_t)(n0 + n) * M + (m0 + mo);
        f32x4 s = *(const f32x4*)src;
#pragma unroll
        for (int zz = 1; zz < KS; ++zz)
            s += *(const f32x4*)(src + (size_t)zz * zs);
        tile[mo + 0][n] = fmaxf(s[0], 0.f);
        tile[mo + 1][n] = fmaxf(s[1], 0.f);
        tile[mo + 2][n] = fmaxf(s[2], 0.f);
        tile[mo + 3][n] = fmaxf(s[3], 0.f);
    }
    __syncthreads();
#pragma unroll
    for (int pass = 0; pass < 4; ++pass) {
        int mm = pass * 16 + (t >> 4);
        int c  = (t & 15) * 4;
        ushort4 o4;
        o4.x = f2bf(tile[mm][c + 0]);
        o4.y = f2bf(tile[mm][c + 1]);
        o4.z = f2bf(tile[mm][c + 2]);
        o4.w = f2bf(tile[mm][c + 3]);
        *(ushort4*)(out + (size_t)(m0 + mm) * H + (n0 + c)) = o4;
    }
}

// p fp32 [KS][64][M] partial logits (transposed); out [M][64] fp32 log_softmax
template<int KS>
__global__ __launch_bounds__(64)
void reduce_lsm(const float* __restrict__ p, float* __restrict__ out, int M)
{
    int m = blockIdx.x * 64 + threadIdx.x;
    const size_t zs = (size_t)64 * M;
    float v[64];
#pragma unroll
    for (int j = 0; j < 64; ++j) {
        const float* src = p + (size_t)j * M + m;
        float s = src[0];
#pragma unroll
        for (int zz = 1; zz < KS; ++zz) s += src[(size_t)zz * zs];
        v[j] = s;
    }
    float mx = -1e30f;
#pragma unroll
    for (int j = 0; j < 64; ++j) mx = fmaxf(mx, v[j]);
    float sum = 0.f;
#pragma unroll
    for (int j = 0; j < 64; ++j) sum += __expf(v[j] - mx);
    float ls = mx + __logf(sum);
#pragma unroll
    for (int j = 0; j < 64; j += 4) {
        f32x4 o = {v[j] - ls, v[j + 1] - ls, v[j + 2] - ls, v[j + 3] - ls};
        *(f32x4*)(out + (size_t)m * 64 + j) = o;
    }
}

extern "C" void kernel_launch(void* const* d_in, const int* in_sizes, int n_in,
                              void* d_out, int out_size, void* d_ws, size_t ws_size,
                              hipStream_t stream)
{
    constexpr int N = 8192, FIN = 512, H = 256, O = 64;
    constexpr int KS_H = 4;   // split-K for the H=256 N x N GEMMs (grid 1024 = 4 blk/CU)
    constexpr int KS_O = 8;   // split-K for the O=64  N x N GEMMs (grid 2048 = 8 blk/CU)
    const float* x    = (const float*)d_in[0];
    const float* wav  = (const float*)d_in[1];
    const float* winv = (const float*)d_in[2];
    const float* w1   = (const float*)d_in[3];
    const float* f1   = (const float*)d_in[4];
    const float* w2   = (const float*)d_in[5];
    const float* f2   = (const float*)d_in[6];

    char* p = (char*)d_ws;
    auto alloc = [&](size_t bytes) { char* r = p; p += (bytes + 255) & ~(size_t)255; return r; };
    short* w1T = (short*)alloc((size_t)FIN * H * 2);          // [H, FIN] bf16
    short* w2T = (short*)alloc((size_t)H * O * 2);            // [O, H] bf16
    short* t1T = (short*)alloc((size_t)H * N * 2);            // [H, N] bf16
    short* t2T = (short*)alloc((size_t)H * N * 2);            // [H, N] bf16 (f1-scaled)
    short* hbuf= (short*)alloc((size_t)N * H * 2);            // [N, H] bf16 row-major
    short* t4T = (short*)alloc((size_t)O * N * 2);            // [O, N] bf16
    short* t5T = (short*)alloc((size_t)O * N * 2);            // [O, N] bf16 (f2-scaled)
    float* part= (float*)alloc((size_t)KS_H * H * N * 4);     // 32 MB split-K partials

    transpose_f32_to_bf16<<<(FIN * H + 255) / 256, 256, 0, stream>>>(
        w1, (unsigned short*)w1T, FIN, H);
    transpose_f32_to_bf16<<<(H * O + 255) / 256, 256, 0, stream>>>(
        w2, (unsigned short*)w2T, H, O);

    // G1: t1T = (x @ w1)^T  (K=512, short loop -> keep direct)
    gemm_bt<64,128,0,true,1><<<dim3(N/64, H/128), 256, 0, stream>>>(
        x, w1T, t1T, nullptr, N, FIN, H);

    // G2: winv @ t1, split-K=4 -> fp32 partials; reduce applies f1 scale -> t2T
    gemm_bt<64,128,0,true,KS_H><<<dim3(N/64, H/128, KS_H), 256, 0, stream>>>(
        winv, t1T, part, nullptr, N, N, H);
    reduce_scaleT<KS_H,true><<<(H * (N / 4)) / 256, 256, 0, stream>>>(
        part, (unsigned short*)t2T, f1, (size_t)H * N);

    // G3: wav @ t2s, split-K=4; reduce applies relu + transpose -> hbuf [N,H] row-major
    gemm_bt<64,128,0,true,KS_H><<<dim3(N/64, H/128, KS_H), 256, 0, stream>>>(
        wav, t2T, part, nullptr, N, N, H);
    reduce_relu_trans<KS_H><<<dim3(N/64, H/64), 256, 0, stream>>>(
        part, (unsigned short*)hbuf, N, H);

    // G4: t4T = (h @ w2)^T  (K=256, direct; BM=32 -> 256 blocks)
    gemm_bt<32,64,0,false,1><<<dim3(N/32, O/64), 256, 0, stream>>>(
        hbuf, w2T, t4T, nullptr, N, H, O);

    // G5: winv @ t4, split-K=8; reduce applies f2 scale -> t5T
    gemm_bt<32,64,0,true,KS_O><<<dim3(N/32, O/64, KS_O), 256, 0, stream>>>(
        winv, t4T, part, nullptr, N, N, O);
    reduce_scaleT<KS_O,true><<<(O * (N / 4)) / 256, 256, 0, stream>>>(
        part, (unsigned short*)t5T, f2, (size_t)O * N);

    // G6: wav @ t5s, split-K=8; reduce fuses z-sum + log_softmax -> d_out
    gemm_bt<32,64,0,true,KS_O><<<dim3(N/32, O/64, KS_O), 256, 0, stream>>>(
        wav, t5T, part, nullptr, N, N, O);
    reduce_lsm<KS_O><<<N / 64, 64, 0, stream>>>(part, (float*)d_out, N);
}